// Round 1
// baseline (284.655 us; speedup 1.0000x reference)
//
#include <hip/hip_runtime.h>
#include <hip/hip_bf16.h>

#define NUM_NODES 200000
#define NUM_EDGES 640000
#define RANK 16
#define EMBED_DIM 128

// ---------------------------------------------------------------------------
// K1: detect edge_index element width. Inspect odd 32-bit words in the first
// in_sizes[2] words (safe under both layouts). int64 layout => those are high
// halves of src indices (< 2^31) => all zero. int32 layout => random node ids
// => essentially surely nonzero. flag=1 means int32.
// ---------------------------------------------------------------------------
__global__ void detect_idx_dtype(const unsigned int* __restrict__ words,
                                 int nwords, int* __restrict__ flag) {
    unsigned int v = 0;
    int stride = gridDim.x * blockDim.x;
    for (int i = blockIdx.x * blockDim.x + threadIdx.x; 2 * i + 1 < nwords; i += stride)
        v |= words[2 * i + 1];
    if (__any(v != 0)) {
        if ((threadIdx.x & 63) == 0) atomicOr(flag, 1);
    }
}

// ---------------------------------------------------------------------------
// K2: rank-space scatter. 16 lanes per edge; lane j adds U[src][j] into
// Usum[dst][j]; lane 0 bumps counts[dst].
// ---------------------------------------------------------------------------
__global__ void scatter_rank(const float* __restrict__ U,
                             const void* __restrict__ edge_index,
                             float* __restrict__ Usum,
                             float* __restrict__ counts,
                             const int* __restrict__ flag,
                             int E) {
    int gid = blockIdx.x * 256 + threadIdx.x;
    int e = gid >> 4;
    int j = gid & 15;
    if (e >= E) return;
    int src, dst;
    if (*flag) {  // int32 layout
        const int* ei = (const int*)edge_index;
        src = ei[e];
        dst = ei[E + e];
    } else {      // int64 layout
        const long long* ei = (const long long*)edge_index;
        src = (int)ei[e];
        dst = (int)ei[E + e];
    }
    atomicAdd(&Usum[(size_t)dst * RANK + j], U[(size_t)src * RANK + j]);
    if (j == 0) atomicAdd(&counts[dst], 1.0f);
}

// ---------------------------------------------------------------------------
// K3: project Usum[N,16] @ V[16,128], divide by max(count,1), write out.
// One thread per output element; 128 threads share one node's Usum row
// (wave-uniform loads); V staged in LDS (8 KB); coalesced output stores.
// ---------------------------------------------------------------------------
__global__ void project_out(const float* __restrict__ Usum,
                            const float* __restrict__ counts,
                            const float* __restrict__ V,
                            float* __restrict__ out) {
    __shared__ float Vs[RANK * EMBED_DIM];
    int t = threadIdx.x;
    // stage V: 2048 floats, 256 threads, float4 => 2 vec-loads/thread
    const float4* V4 = (const float4*)V;
    float4* Vs4 = (float4*)Vs;
    for (int i = t; i < RANK * EMBED_DIM / 4; i += 256) Vs4[i] = V4[i];
    __syncthreads();

    int gid = blockIdx.x * 256 + t;       // < N*128 = 25.6M, fits int
    int n = gid >> 7;
    int d = gid & 127;

    const float4* Us4 = (const float4*)(Usum + (size_t)n * RANK);
    float4 a0 = Us4[0], a1 = Us4[1], a2 = Us4[2], a3 = Us4[3];

    float acc = 0.f;
    const float* vc = Vs + d;
    acc += a0.x * vc[0 * EMBED_DIM] + a0.y * vc[1 * EMBED_DIM] +
           a0.z * vc[2 * EMBED_DIM] + a0.w * vc[3 * EMBED_DIM];
    acc += a1.x * vc[4 * EMBED_DIM] + a1.y * vc[5 * EMBED_DIM] +
           a1.z * vc[6 * EMBED_DIM] + a1.w * vc[7 * EMBED_DIM];
    acc += a2.x * vc[8 * EMBED_DIM] + a2.y * vc[9 * EMBED_DIM] +
           a2.z * vc[10 * EMBED_DIM] + a2.w * vc[11 * EMBED_DIM];
    acc += a3.x * vc[12 * EMBED_DIM] + a3.y * vc[13 * EMBED_DIM] +
           a3.z * vc[14 * EMBED_DIM] + a3.w * vc[15 * EMBED_DIM];

    float c = counts[n];
    float denom = fmaxf(c, 1.0f);
    out[gid] = acc / denom;
}

extern "C" void kernel_launch(void* const* d_in, const int* in_sizes, int n_in,
                              void* d_out, int out_size, void* d_ws, size_t ws_size,
                              hipStream_t stream) {
    const float* U = (const float*)d_in[0];
    const float* V = (const float*)d_in[1];
    const void* EI = d_in[2];
    float* out = (float*)d_out;

    const int N = in_sizes[0] / RANK;      // 200000
    const int E = in_sizes[2] / 2;         // 640000

    // workspace layout: Usum[N*16] | counts[N] | flag[1]
    float* Usum = (float*)d_ws;
    float* counts = Usum + (size_t)N * RANK;
    int* flag = (int*)(counts + N);
    size_t zero_bytes = ((size_t)N * RANK + N + 1) * sizeof(float);

    hipMemsetAsync(d_ws, 0, zero_bytes, stream);

    detect_idx_dtype<<<256, 256, 0, stream>>>((const unsigned int*)EI,
                                              in_sizes[2], flag);

    int scatter_threads = E * RANK;        // 10.24M
    scatter_rank<<<(scatter_threads + 255) / 256, 256, 0, stream>>>(
        U, EI, Usum, counts, flag, E);

    int proj_blocks = (int)(((size_t)N * EMBED_DIM) / 256);  // 100000
    project_out<<<proj_blocks, 256, 0, stream>>>(Usum, counts, V, out);
}

// Round 2
// 200.243 us; speedup vs baseline: 1.4215x; 1.4215x over previous
//
#include <hip/hip_runtime.h>
#include <hip/hip_bf16.h>

#define RANK 16
#define EMBED_DIM 128

// ---------------------------------------------------------------------------
// K1: detect edge_index element width. int64 layout => odd 32-bit words are
// high halves of node ids (< 2^31) => all zero. int32 layout => random node
// ids => essentially surely nonzero. flag=1 means int32.
// Only the first 2048 pairs are inspected (one block) — deterministic and
// statistically unambiguous.
// ---------------------------------------------------------------------------
__global__ void detect_idx_dtype(const unsigned int* __restrict__ words,
                                 int nwords, int* __restrict__ flag) {
    unsigned int v = 0;
    for (int i = threadIdx.x; i < 2048; i += 256) {
        int w = 2 * i + 1;
        if (w < nwords) v |= words[w];
    }
    if (__any(v != 0)) {
        if ((threadIdx.x & 63) == 0) atomicOr(flag, 1);
    }
}

// ---------------------------------------------------------------------------
// K2: rank-space scatter (unchanged from R1 for clean attribution).
// 16 lanes per edge; lane j adds U[src][j] into Usum[dst][j]; lane 0 bumps
// counts[dst].
// ---------------------------------------------------------------------------
__global__ void scatter_rank(const float* __restrict__ U,
                             const void* __restrict__ edge_index,
                             float* __restrict__ Usum,
                             float* __restrict__ counts,
                             const int* __restrict__ flag,
                             int E) {
    int gid = blockIdx.x * 256 + threadIdx.x;
    int e = gid >> 4;
    int j = gid & 15;
    if (e >= E) return;
    int src, dst;
    if (*flag) {  // int32 layout
        const int* ei = (const int*)edge_index;
        src = ei[e];
        dst = ei[E + e];
    } else {      // int64 layout (little-endian: low word at 2*e)
        const int* ei = (const int*)edge_index;
        src = ei[2 * e];
        dst = ei[2 * (E + e)];
    }
    atomicAdd(&Usum[(size_t)dst * RANK + j], U[(size_t)src * RANK + j]);
    if (j == 0) atomicAdd(&counts[dst], 1.0f);
}

// ---------------------------------------------------------------------------
// K3: project Usum[N,16] @ V[16,128] / max(count,1) -> out[N,128].
// Block = 256 threads handles 32 nodes. Thread (q = t&31, w = t>>5) computes
// a 4-node x 4-column tile: float4 LDS reads (ds_read_b128), float4 stores,
// V-column reads amortized over 4 nodes (16 B LDS / output vs 64 B before).
// ---------------------------------------------------------------------------
__global__ __launch_bounds__(256) void project_out(
        const float* __restrict__ Usum,
        const float* __restrict__ counts,
        const float* __restrict__ V,
        float* __restrict__ out) {
    __shared__ float4 Vs4[RANK * EMBED_DIM / 4];  // 512 float4 = 8 KB
    int t = threadIdx.x;
    const float4* V4 = (const float4*)V;
    Vs4[t] = V4[t];
    Vs4[t + 256] = V4[t + 256];
    __syncthreads();

    int q = t & 31;          // column group: cols 4q..4q+3
    int w = t >> 5;          // 0..7
    int n0 = blockIdx.x * 32 + 4 * w;  // nodes n0..n0+3

    const float4* Us4 = (const float4*)Usum;
    float4 a[4][4];
#pragma unroll
    for (int r = 0; r < 4; ++r)
#pragma unroll
        for (int k4 = 0; k4 < 4; ++k4)
            a[r][k4] = Us4[(size_t)(n0 + r) * 4 + k4];

    float4 acc[4];
#pragma unroll
    for (int r = 0; r < 4; ++r) acc[r] = make_float4(0.f, 0.f, 0.f, 0.f);

#pragma unroll
    for (int k = 0; k < RANK; ++k) {
        float4 v = Vs4[k * 32 + q];
#pragma unroll
        for (int r = 0; r < 4; ++r) {
            float ar = (k & 3) == 0 ? a[r][k >> 2].x
                     : (k & 3) == 1 ? a[r][k >> 2].y
                     : (k & 3) == 2 ? a[r][k >> 2].z
                                    : a[r][k >> 2].w;
            acc[r].x = fmaf(ar, v.x, acc[r].x);
            acc[r].y = fmaf(ar, v.y, acc[r].y);
            acc[r].z = fmaf(ar, v.z, acc[r].z);
            acc[r].w = fmaf(ar, v.w, acc[r].w);
        }
    }

    float4* out4 = (float4*)out;
#pragma unroll
    for (int r = 0; r < 4; ++r) {
        float c = counts[n0 + r];
        float s = 1.0f / fmaxf(c, 1.0f);
        out4[(size_t)(n0 + r) * (EMBED_DIM / 4) + q] =
            make_float4(acc[r].x * s, acc[r].y * s, acc[r].z * s, acc[r].w * s);
    }
}

extern "C" void kernel_launch(void* const* d_in, const int* in_sizes, int n_in,
                              void* d_out, int out_size, void* d_ws, size_t ws_size,
                              hipStream_t stream) {
    const float* U = (const float*)d_in[0];
    const float* V = (const float*)d_in[1];
    const void* EI = d_in[2];
    float* out = (float*)d_out;

    const int N = in_sizes[0] / RANK;      // 200000
    const int E = in_sizes[2] / 2;         // 640000

    // workspace layout: Usum[N*16] | counts[N] | flag[1]
    float* Usum = (float*)d_ws;
    float* counts = Usum + (size_t)N * RANK;
    int* flag = (int*)(counts + N);
    size_t zero_bytes = ((size_t)N * RANK + N + 1) * sizeof(float);

    hipMemsetAsync(d_ws, 0, zero_bytes, stream);

    detect_idx_dtype<<<1, 256, 0, stream>>>((const unsigned int*)EI,
                                            in_sizes[2], flag);

    int scatter_threads = E * RANK;        // 10.24M
    scatter_rank<<<(scatter_threads + 255) / 256, 256, 0, stream>>>(
        U, EI, Usum, counts, flag, E);

    project_out<<<N / 32, 256, 0, stream>>>(Usum, counts, V, out);
}